// Round 8
// baseline (290.109 us; speedup 1.0000x reference)
//
#include <hip/hip_runtime.h>
#include <math.h>

#define EPSF   1e-6f
#define SCALE  0.125f          // 1/sqrt(D), D=64
#define NEG_HUGE -3.402823466e38f

// K3 p_k_i LDS layout: [4 kq blocks][256 t][4], stride skewed to 1032 floats
// (1032 % 32 == 8) -> the 4 per-wave read addresses hit 4 disjoint 4-bank
// groups -> conflict-free ds_read_b128.
#define PW_STRIDE 1032

// workspace float layout
#define WS_SCORES 0                          // [512][1024]
#define WS_PI     (512*1024)                 // [512][1024]
#define WS_PART   (2*512*1024)               // [512][4][16][64]
#define WS_GP     (WS_PART + 512*4*16*64)    // [16][64]   g0*pn
#define WS_SGPBP  (WS_GP + 16*64)            // [32]       sGP | BP
#define WS_G2Q    (WS_SGPBP + 32)            // [512][64]  g2*q''
#define WS_CPAIR  (WS_G2Q + 512*64)          // [512][2]   {sum(G2Q), b2.q''+Wb.q}

__device__ __forceinline__ float rs_nr(float x) {
    float r = rsqrtf(x);
    return r * (1.5f - 0.5f * x * r * r);   // one Newton step -> ~f32 accurate
}

// ---------------- K0: per-batch q-prologue (blocks 0..511) + proto (block 512) --
__global__ __launch_bounds__(64)
void k0_prologue(const float* __restrict__ z, const float* __restrict__ proto,
                 const float* __restrict__ alphas, const float* __restrict__ b_bias,
                 const float* __restrict__ W, const float* __restrict__ Wb,
                 const float* __restrict__ lng, const float* __restrict__ lnb,
                 float* __restrict__ ws)
{
    const int lane = threadIdx.x;
    if (blockIdx.x == 512) {
        // pn = LN(prototypes_k); GP = g0*pn; sGP = sum(GP); BP = b0.pn
        if (lane < 16) {
            const int k = lane;
            float s1 = 0.f, s2 = 0.f;
#pragma unroll 4
            for (int qd = 0; qd < 16; ++qd) {
                float4 p = *(const float4*)&proto[k*64 + qd*4];
                s1 += (p.x + p.y) + (p.z + p.w);
                s2 = fmaf(p.x,p.x, fmaf(p.y,p.y, fmaf(p.z,p.z, fmaf(p.w,p.w, s2))));
            }
            float m  = s1 * (1.f/64.f);
            float v  = s2 * (1.f/64.f) - m*m;
            float rs = rs_nr(v + EPSF);
            float sgp = 0.f, bp = 0.f;
            for (int d = 0; d < 64; ++d) {
                float pn = fmaf((proto[k*64 + d] - m) * rs, lng[64 + d], lnb[64 + d]);
                float g  = lng[d] * pn;
                ws[WS_GP + k*64 + d] = g;
                sgp += g;
                bp = fmaf(lnb[d], pn, bp);
            }
            ws[WS_SGPBP + k]      = sgp;
            ws[WS_SGPBP + 16 + k] = bp;
        }
    } else {
        // q = LN(alphas[-1] + z[b,-1] + b_bias); q'' = q + W@q; G2Q = g2*q''
        const int b = blockIdx.x;
        const int d = lane;
        const float* zb = z + (size_t)b * 65536;
        float a = alphas[1023*64 + d] + zb[1023*64 + d] + b_bias[d];
        float s1 = a, s2 = a*a;
#pragma unroll
        for (int off = 32; off >= 1; off >>= 1) {
            s1 += __shfl_xor(s1, off);
            s2 += __shfl_xor(s2, off);
        }
        float m  = s1 * (1.f/64.f);
        float v  = s2 * (1.f/64.f) - m*m;
        float rs = rs_nr(v + EPSF);
        float qd = fmaf((a - m) * rs, lng[3*64 + d], lnb[3*64 + d]);
        float s = 0.f;
#pragma unroll 4
        for (int eq = 0; eq < 16; ++eq) {
            float4 w4 = *(const float4*)&W[d*64 + eq*4];
            s = fmaf(w4.x, __shfl(qd, 4*eq+0),
                fmaf(w4.y, __shfl(qd, 4*eq+1),
                fmaf(w4.z, __shfl(qd, 4*eq+2),
                fmaf(w4.w, __shfl(qd, 4*eq+3), s))));
        }
        float qpp  = qd + s;
        float G2Qd = lng[2*64 + d] * qpp;
        ws[WS_G2Q + b*64 + d] = G2Qd;
        float r1 = G2Qd;
        float r2 = fmaf(lnb[2*64 + d], qpp, Wb[d] * qd);
#pragma unroll
        for (int off = 32; off >= 1; off >>= 1) {
            r1 += __shfl_xor(r1, off);
            r2 += __shfl_xor(r2, off);
        }
        if (d == 0) { ws[WS_CPAIR + b*2] = r1; ws[WS_CPAIR + b*2 + 1] = r2; }
    }
}

// ---------------- K1: scores_t, 4 lanes per token (coalesced) -----------------
// grid 8192 = 512 b x 16 slices, 256 thr -> 64 tokens/block
__global__ __launch_bounds__(256, 8)
void k1_scores(const float* __restrict__ z, const float* __restrict__ alphas,
               const float* __restrict__ ws_ro, float* __restrict__ ws)
{
    const int b     = blockIdx.x >> 4;
    const int slice = blockIdx.x & 15;
    const int tid   = threadIdx.x;
    const int qg    = tid & 3;                 // quad-group within token
    const int t     = slice*64 + (tid >> 2);
    const float* zb = z + (size_t)b * 65536;

    const float sG2Q = ws_ro[WS_CPAIR + b*2];      // block-uniform -> scalar
    const float TQc  = ws_ro[WS_CPAIR + b*2 + 1];
    const float* g2qb = ws_ro + WS_G2Q + b*64;

    float sa = 0.f, saa = 0.f, da = 0.f;
#pragma unroll
    for (int i = 0; i < 4; ++i) {
        const int qd = qg + i*4;               // lanes 0..3 cover 64B contiguous
        float4 zq = *(const float4*)&zb[(size_t)t*64 + qd*4];
        float4 aq = *(const float4*)&alphas[(size_t)t*64 + qd*4];
        float4 gq = *(const float4*)&g2qb[qd*4];
        float ux = zq.x+aq.x, uy = zq.y+aq.y, uz = zq.z+aq.z, uw = zq.w+aq.w;
        sa += (ux+uy)+(uz+uw);
        saa = fmaf(ux,ux, fmaf(uy,uy, fmaf(uz,uz, fmaf(uw,uw, saa))));
        da  = fmaf(ux,gq.x, fmaf(uy,gq.y, fmaf(uz,gq.z, fmaf(uw,gq.w, da))));
    }
    // reduce across the 4-lane group
    sa  += __shfl_xor(sa, 1);  sa  += __shfl_xor(sa, 2);
    saa += __shfl_xor(saa, 1); saa += __shfl_xor(saa, 2);
    da  += __shfl_xor(da, 1);  da  += __shfl_xor(da, 2);

    float ma   = sa  * (1.f/64.f);
    float vara = saa * (1.f/64.f) - ma*ma;
    float rsa  = rs_nr(vara + EPSF);
    float st   = (rsa * (da - ma * sG2Q) + TQc) * SCALE;
    if (qg == 0) ws[WS_SCORES + b*1024 + t] = st;   // 16 consecutive floats/wave
}

// ---------------- K2: softmax over T per batch --------------------------------
__global__ __launch_bounds__(256, 8)
void k2_softmax(const float* __restrict__ ws_ro, float* __restrict__ ws)
{
    const int b = blockIdx.x;
    const int tid = threadIdx.x, lane = tid & 63, wid = tid >> 6;
    __shared__ float s_red[6];
    float4 s4 = *(const float4*)&ws_ro[WS_SCORES + b*1024 + tid*4];
    float lm = fmaxf(fmaxf(s4.x, s4.y), fmaxf(s4.z, s4.w));
#pragma unroll
    for (int off = 32; off >= 1; off >>= 1) lm = fmaxf(lm, __shfl_xor(lm, off));
    if (lane == 0) s_red[wid] = lm;
    __syncthreads();
    if (tid == 0)
        s_red[4] = fmaxf(fmaxf(s_red[0], s_red[1]), fmaxf(s_red[2], s_red[3]));
    __syncthreads();
    float M = s_red[4];
    float e0 = __expf(s4.x - M), e1 = __expf(s4.y - M);
    float e2 = __expf(s4.z - M), e3 = __expf(s4.w - M);
    float ls = (e0 + e1) + (e2 + e3);
#pragma unroll
    for (int off = 32; off >= 1; off >>= 1) ls += __shfl_xor(ls, off);
    if (lane == 0) s_red[wid] = ls;
    __syncthreads();
    if (tid == 0) s_red[5] = 1.f / (s_red[0] + s_red[1] + s_red[2] + s_red[3]);
    __syncthreads();
    float invZ = s_red[5];
    *(float4*)&ws[WS_PI + b*1024 + tid*4] =
        make_float4(e0*invZ, e1*invZ, e2*invZ, e3*invZ);
}

// ---------------- K3: p_k_i + weighted aggregation (partials) ----------------
// grid 2048 = 512 b x 4 slices, 256 thr, 1 token/thread (256 tokens/block)
__global__ __launch_bounds__(256, 8)
void k3_aggr(const float* __restrict__ z, const float* __restrict__ ws_ro,
             float* __restrict__ ws)
{
    const int b     = blockIdx.x >> 2;
    const int slice = blockIdx.x & 3;
    const int tid   = threadIdx.x;
    const int lane  = tid & 63;
    const int wid   = tid >> 6;
    const int tbase = slice * 256;
    const float* zb = z + (size_t)b * 65536;
    const float* gp = ws_ro + WS_GP;          // block-uniform reads -> scalar path

    __shared__ __align__(16) float s_pw[4 * PW_STRIDE];   // 16.5KB, aliased below

    // ---- phase A-lite: z-LN stats + 16 prototype dots (no LDS, no alphas) ----
    const float pi_t = ws_ro[WS_PI + b*1024 + tbase + tid];
    {
        const float4* zp = (const float4*)(zb + (size_t)(tbase + tid) * 64);
        float dk[16];
#pragma unroll
        for (int k = 0; k < 16; ++k) dk[k] = 0.f;
        float sz = 0.f, szz = 0.f;
#pragma unroll 2
        for (int qd = 0; qd < 16; ++qd) {
            float4 zq = zp[qd];
            sz += (zq.x + zq.y) + (zq.z + zq.w);
            szz = fmaf(zq.x,zq.x, fmaf(zq.y,zq.y, fmaf(zq.z,zq.z, fmaf(zq.w,zq.w, szz))));
#pragma unroll
            for (int k = 0; k < 16; ++k) {
                float4 g = *(const float4*)&gp[k*64 + qd*4];   // uniform -> s_load
                dk[k] = fmaf(zq.x,g.x, fmaf(zq.y,g.y,
                        fmaf(zq.z,g.z, fmaf(zq.w,g.w, dk[k]))));
            }
        }
        float m   = sz  * (1.f/64.f);
        float var = szz * (1.f/64.f) - m*m;
        float rs  = rs_nr(var + EPSF);
        float sk[16];
        float mx = NEG_HUGE;
#pragma unroll
        for (int k = 0; k < 16; ++k) {
            float s = (rs * (dk[k] - m * ws_ro[WS_SGPBP + k]) + ws_ro[WS_SGPBP + 16 + k]) * SCALE;
            sk[k] = s;
            mx = fmaxf(mx, s);
        }
        float se = 0.f;
#pragma unroll
        for (int k = 0; k < 16; ++k) { sk[k] = __expf(sk[k] - mx); se += sk[k]; }
        const float c = pi_t / se;            // w[t,k] = p_k_i * p_i
#pragma unroll
        for (int kq = 0; kq < 4; ++kq) {
            float4 w4 = make_float4(sk[4*kq+0]*c, sk[4*kq+1]*c,
                                    sk[4*kq+2]*c, sk[4*kq+3]*c);
            *(float4*)&s_pw[kq*PW_STRIDE + tid*4] = w4;   // lane-consecutive 16B
        }
    }
    __syncthreads();

    // ---- phase B: partial out[k][d] over this slice's 256 tokens -------------
    const int kq = lane >> 4;     // 0..3
    const int dq = lane & 15;     // 0..15
    float acc[4][4];
#pragma unroll
    for (int i = 0; i < 4; ++i)
#pragma unroll
        for (int j = 0; j < 4; ++j) acc[i][j] = 0.f;

#pragma unroll 4
    for (int tt = 0; tt < 64; ++tt) {
        const int tl = wid*64 + tt;   // each of 4 waves owns 64 tokens
        float4 zq = *(const float4*)&zb[(size_t)(tbase + tl)*64 + dq*4];
        float4 wq = *(const float4*)&s_pw[kq*PW_STRIDE + tl*4];
        float zv[4] = { zq.x, zq.y, zq.z, zq.w };
        float wv[4] = { wq.x, wq.y, wq.z, wq.w };
#pragma unroll
        for (int i = 0; i < 4; ++i)
#pragma unroll
            for (int j = 0; j < 4; ++j)
                acc[i][j] = fmaf(wv[i], zv[j], acc[i][j]);
    }
    __syncthreads();              // all pw reads done -> safe to alias buffer

    float* s_part = s_pw;         // [4 waves][16 k][64 d] = 16KB <= 16.5KB
#pragma unroll
    for (int i = 0; i < 4; ++i) {
        float4 v = make_float4(acc[i][0], acc[i][1], acc[i][2], acc[i][3]);
        *(float4*)&s_part[wid*1024 + (kq*4 + i)*64 + dq*4] = v;
    }
    __syncthreads();

    {   // reduce 4 wave-slabs -> ws_part[b][slice][k][d]
        const int k  = tid >> 4;
        const int dg = tid & 15;
        float4 v = make_float4(0.f, 0.f, 0.f, 0.f);
#pragma unroll
        for (int w = 0; w < 4; ++w) {
            float4 p = *(const float4*)&s_part[w*1024 + k*64 + dg*4];
            v.x += p.x; v.y += p.y; v.z += p.z; v.w += p.w;
        }
        *(float4*)&ws[WS_PART + (((size_t)b*4 + slice)*16 + k)*64 + dg*4] = v;
    }
}

// ---------------- K4: reduce slices + beta_seq + final LN ---------------------
__global__ __launch_bounds__(256, 8)
void k4_final(const float* __restrict__ ws_ro, const float* __restrict__ beta_seq,
              const float* __restrict__ lng, const float* __restrict__ lnb,
              float* __restrict__ out)
{
    const int b   = blockIdx.x;
    const int tid = threadIdx.x;
    const int k   = tid >> 4;
    const int dg  = tid & 15;
    float4 v = make_float4(0.f, 0.f, 0.f, 0.f);
#pragma unroll
    for (int s = 0; s < 4; ++s) {
        float4 p = *(const float4*)&ws_ro[WS_PART + (((size_t)b*4 + s)*16 + k)*64 + dg*4];
        v.x += p.x; v.y += p.y; v.z += p.z; v.w += p.w;
    }
    float4 bs = *(const float4*)&beta_seq[k*64 + dg*4];
    v.x += bs.x; v.y += bs.y; v.z += bs.z; v.w += bs.w;

    float s1 = (v.x + v.y) + (v.z + v.w);
    float s2 = fmaf(v.x,v.x, fmaf(v.y,v.y, fmaf(v.z,v.z, v.w*v.w)));
#pragma unroll
    for (int off = 1; off <= 8; off <<= 1) {   // 16-lane group reduce
        s1 += __shfl_xor(s1, off);
        s2 += __shfl_xor(s2, off);
    }
    float m   = s1 * (1.f/64.f);
    float var = s2 * (1.f/64.f) - m*m;
    float rs  = rs_nr(var + EPSF);
    float4 g4 = *(const float4*)&lng[4*64 + dg*4];
    float4 b4 = *(const float4*)&lnb[4*64 + dg*4];
    float4 o;
    o.x = fmaf((v.x - m)*rs, g4.x, b4.x);
    o.y = fmaf((v.y - m)*rs, g4.y, b4.y);
    o.z = fmaf((v.z - m)*rs, g4.z, b4.z);
    o.w = fmaf((v.w - m)*rs, g4.w, b4.w);
    *(float4*)&out[((size_t)b*16 + k)*64 + dg*4] = o;
}

extern "C" void kernel_launch(void* const* d_in, const int* in_sizes, int n_in,
                              void* d_out, int out_size, void* d_ws, size_t ws_size,
                              hipStream_t stream) {
    const float* z        = (const float*)d_in[0];
    const float* proto    = (const float*)d_in[1];
    const float* alphas   = (const float*)d_in[2];
    const float* b_bias   = (const float*)d_in[3];
    const float* W        = (const float*)d_in[4];
    const float* Wb       = (const float*)d_in[5];
    const float* lng      = (const float*)d_in[6];
    const float* lnb      = (const float*)d_in[7];
    const float* beta_seq = (const float*)d_in[8];
    float* out = (float*)d_out;
    float* ws  = (float*)d_ws;     // needs ~12.7MB

    k0_prologue<<<dim3(513),  dim3(64),  0, stream>>>(z, proto, alphas, b_bias,
                                                      W, Wb, lng, lnb, ws);
    k1_scores  <<<dim3(8192), dim3(256), 0, stream>>>(z, alphas, ws, ws);
    k2_softmax <<<dim3(512),  dim3(256), 0, stream>>>(ws, ws);
    k3_aggr    <<<dim3(2048), dim3(256), 0, stream>>>(z, ws, ws);
    k4_final   <<<dim3(512),  dim3(256), 0, stream>>>(ws, beta_seq, lng, lnb, out);
}